// Round 3
// baseline (452.304 us; speedup 1.0000x reference)
//
#include <hip/hip_runtime.h>

#define HD 1024
#define NS 64
#define NB 8
#define LS 2048
#define MT (NB*LS)        // 16384 rows
#define N2 128            // 2*NS
#define KA 1152           // HD + N2, A/B leading dim (K-extended)
#define CHL 16            // scan chunk length
#define NCH (LS/CHL)      // 128 chunks

typedef __attribute__((ext_vector_type(8))) short short8;
typedef __attribute__((ext_vector_type(4))) float f32x4;

// ---- workspace byte offsets -------------------------------------------------
#define OB_ABUF 0u                               // bf16 [16384][1152]
#define OB_BMAT (OB_ABUF + MT*KA*2)              // bf16 [1024][1152]
#define OB_BMP  (OB_BMAT + HD*KA*2)              // bf16 [128][1024]
#define OB_BU   (OB_BMP  + N2*HD*2)              // f32  [16384][128]
#define OB_FR   (OB_BU   + MT*N2*4)              // f32  [8*64*128]
#define OB_FI   (OB_FR   + NB*NS*NCH*4)
#define OB_CR   (OB_FI   + NB*NS*NCH*4)
#define OB_CI   (OB_CR   + NB*NS*NCH*4)
// end ~ 49.8 MB

__device__ __forceinline__ unsigned short f2bf(float f) {
    unsigned u = __float_as_uint(f);
    u = (u + 0x7FFFu + ((u >> 16) & 1u)) >> 16;
    return (unsigned short)u;
}

__device__ __forceinline__ void lbar_of(int n, const float* __restrict__ logLr,
                                        const float* __restrict__ Li, float dt,
                                        float& ar, float& ai) {
    float lr  = -expf(logLr[n]);
    float mag = expf(lr * dt);
    float ang = Li[n] * dt;
    ar = mag * cosf(ang);
    ai = mag * sinf(ang);
}

// ---------------- fused prep: cast x / D*W / dt*B ---------------------------
// blocks [0,8192): Abuf cols 0..1023 = bf16(x)
// blocks [8192,8704): Bmat cols 0..1023 = bf16(D[k]*W[h,k])
// blocks [8704,8768): Bmp[n2][k] = bf16(dt*(Br|Bi))
__global__ __launch_bounds__(256) void k_prep(const float* __restrict__ x,
                                              const float* __restrict__ W,
                                              const float* __restrict__ Dv,
                                              const float* __restrict__ Br,
                                              const float* __restrict__ Bi,
                                              const float* __restrict__ log_dt,
                                              unsigned short* __restrict__ Ab,
                                              unsigned short* __restrict__ Bm,
                                              unsigned short* __restrict__ Bp) {
    const int blk = blockIdx.x;
    if (blk < 8192) {
        size_t idx = ((size_t)blk * 256 + threadIdx.x) * 8;
        int m = (int)(idx >> 10), k = (int)(idx & 1023);
        float4 v0 = *(const float4*)&x[idx];
        float4 v1 = *(const float4*)&x[idx + 4];
        short8 s;
        s[0]=f2bf(v0.x); s[1]=f2bf(v0.y); s[2]=f2bf(v0.z); s[3]=f2bf(v0.w);
        s[4]=f2bf(v1.x); s[5]=f2bf(v1.y); s[6]=f2bf(v1.z); s[7]=f2bf(v1.w);
        *(short8*)&Ab[(size_t)m * KA + k] = s;
    } else if (blk < 8704) {
        size_t idx = ((size_t)(blk - 8192) * 256 + threadIdx.x) * 8;
        int h = (int)(idx >> 10), k = (int)(idx & 1023);
        float4 v0 = *(const float4*)&W[idx];
        float4 v1 = *(const float4*)&W[idx + 4];
        float4 d0 = *(const float4*)&Dv[k];
        float4 d1 = *(const float4*)&Dv[k + 4];
        short8 s;
        s[0]=f2bf(v0.x*d0.x); s[1]=f2bf(v0.y*d0.y); s[2]=f2bf(v0.z*d0.z); s[3]=f2bf(v0.w*d0.w);
        s[4]=f2bf(v1.x*d1.x); s[5]=f2bf(v1.y*d1.y); s[6]=f2bf(v1.z*d1.z); s[7]=f2bf(v1.w*d1.w);
        *(short8*)&Bm[(size_t)h * KA + k] = s;
    } else {
        size_t idx = ((size_t)(blk - 8704) * 256 + threadIdx.x) * 8;
        int n2 = (int)(idx >> 10), k = (int)(idx & 1023);
        float dt = expf(log_dt[0]);
        const float* src = (n2 < NS) ? &Br[(size_t)n2 * HD + k] : &Bi[(size_t)(n2 - NS) * HD + k];
        float4 v0 = *(const float4*)&src[0];
        float4 v1 = *(const float4*)&src[4];
        short8 s;
        s[0]=f2bf(v0.x*dt); s[1]=f2bf(v0.y*dt); s[2]=f2bf(v0.z*dt); s[3]=f2bf(v0.w*dt);
        s[4]=f2bf(v1.x*dt); s[5]=f2bf(v1.y*dt); s[6]=f2bf(v1.z*dt); s[7]=f2bf(v1.w*dt);
        *(short8*)&Bp[(size_t)n2 * HD + k] = s;
    }
}

// ---------------- E2T[h2][n2] = sum_k W[h2,k]*(Cr|-Ci)[k][n2] ---------------
// 256 blocks x 4 h-rows; sign folded into LDS stage.
__global__ __launch_bounds__(256) void k_e2(const float* __restrict__ W,
                                            const float* __restrict__ Cr,
                                            const float* __restrict__ Ci,
                                            unsigned short* __restrict__ Bm) {
    __shared__ float Cs[32][128 + 2];
    __shared__ float Ws[4][32];
    const int h0 = blockIdx.x * 4;
    const int tid = threadIdx.x;
    const int n2 = tid & 127, hg = tid >> 7;      // hg in {0,1}
    float acc0 = 0.f, acc1 = 0.f;
    for (int kt = 0; kt < 1024; kt += 32) {
        if (tid < 128) {
            int hl = tid >> 5, kk = tid & 31;
            Ws[hl][kk] = W[(size_t)(h0 + hl) * HD + kt + kk];
        }
        #pragma unroll
        for (int i = 0; i < 16; ++i) {
            int e = tid + i * 256, kk = e >> 7, c = e & 127;
            Cs[kk][c] = (c < NS) ? Cr[(size_t)(kt + kk) * NS + c]
                                 : -Ci[(size_t)(kt + kk) * NS + c - NS];
        }
        __syncthreads();
        #pragma unroll
        for (int kk = 0; kk < 32; ++kk) {
            float cv = Cs[kk][n2];
            acc0 += Ws[hg * 2 + 0][kk] * cv;
            acc1 += Ws[hg * 2 + 1][kk] * cv;
        }
        __syncthreads();
    }
    Bm[(size_t)(h0 + hg * 2 + 0) * KA + HD + n2] = f2bf(acc0);
    Bm[(size_t)(h0 + hg * 2 + 1) * KA + HD + n2] = f2bf(acc1);
}

// ---------------- scan pass A: per-chunk carry-out (from zero state) --------
__global__ __launch_bounds__(256) void k_carry(const float* __restrict__ Bu,
                                               const float* __restrict__ logLr,
                                               const float* __restrict__ Li,
                                               const float* __restrict__ log_dt,
                                               float* __restrict__ Fr,
                                               float* __restrict__ Fi) {
    int g = blockIdx.x * 256 + threadIdx.x;       // 65536 = 8b * 128ch * 64n
    int n = g & 63, ch = (g >> 6) & (NCH - 1), b = g >> 13;
    float dt = expf(log_dt[0]);
    float ar, ai; lbar_of(n, logLr, Li, dt, ar, ai);
    float sr = 0.f, si = 0.f;
    size_t base = ((size_t)b * LS + ch * CHL) * N2;
    #pragma unroll 4
    for (int j = 0; j < CHL; ++j) {
        float ur = Bu[base + j * N2 + n];
        float ui = Bu[base + j * N2 + NS + n];
        float nr = ar * sr - ai * si + ur;
        float ni = ar * si + ai * sr + ui;
        sr = nr; si = ni;
    }
    int fi = (b * NS + n) * NCH + ch;
    Fr[fi] = sr; Fi[fi] = si;
}

// ---------------- scan pass B: carry scan + final states --------------------
__global__ __launch_bounds__(256) void k_scan2(const float* __restrict__ Fr,
                                               const float* __restrict__ Fi,
                                               const float* __restrict__ logLr,
                                               const float* __restrict__ Li,
                                               const float* __restrict__ log_dt,
                                               float* __restrict__ CexR,
                                               float* __restrict__ CexI,
                                               float* __restrict__ out_tail) {
    int g = blockIdx.x * 256 + threadIdx.x;       // 512 = 8b * 64n
    if (g >= NB * NS) return;
    int n = g & 63;
    float dt = expf(log_dt[0]);
    float ar, ai; lbar_of(n, logLr, Li, dt, ar, ai);
    float Ar = ar, Ai = ai;                        // a^16 via 4 squarings
    #pragma unroll
    for (int s = 0; s < 4; ++s) { float nr = Ar*Ar - Ai*Ai; Ai = 2.f*Ar*Ai; Ar = nr; }
    float cr = 0.f, ci = 0.f;
    for (int ch = 0; ch < NCH; ++ch) {
        CexR[g * NCH + ch] = cr; CexI[g * NCH + ch] = ci;
        float fr = Fr[g * NCH + ch], fi2 = Fi[g * NCH + ch];
        float nr = Ar * cr - Ai * ci + fr;
        float ni = Ar * ci + Ai * cr + fi2;
        cr = nr; ci = ni;
    }
    out_tail[g]          = cr;    // sr final (B,N)
    out_tail[NB*NS + g]  = ci;    // si final
}

// ---------------- scan pass C: replay with carry, write bf16 S into Abuf ----
__global__ __launch_bounds__(256) void k_scan3(const float* __restrict__ Bu,
                                               const float* __restrict__ CexR,
                                               const float* __restrict__ CexI,
                                               const float* __restrict__ logLr,
                                               const float* __restrict__ Li,
                                               const float* __restrict__ log_dt,
                                               unsigned short* __restrict__ Ab) {
    int g = blockIdx.x * 256 + threadIdx.x;
    int n = g & 63, ch = (g >> 6) & (NCH - 1), b = g >> 13;
    float dt = expf(log_dt[0]);
    float ar, ai; lbar_of(n, logLr, Li, dt, ar, ai);
    int ci_idx = (b * NS + n) * NCH + ch;
    float sr = CexR[ci_idx], si = CexI[ci_idx];
    size_t base = ((size_t)b * LS + ch * CHL);
    #pragma unroll 4
    for (int j = 0; j < CHL; ++j) {
        size_t m = base + j;
        float ur = Bu[m * N2 + n];
        float ui = Bu[m * N2 + NS + n];
        float nr = ar * sr - ai * si + ur;
        float ni = ar * si + ai * sr + ui;
        sr = nr; si = ni;
        Ab[m * KA + HD + n]      = f2bf(sr);
        Ab[m * KA + HD + NS + n] = f2bf(si);
    }
}

// ---------------- MFMA GEMM: out[M,N] = A[M,K] * B[N,K]^T (+bias) -----------
// 128x128 tile, BK=32, 4 waves (2x2), global_load_lds w=16,
// 2-phase LDS double-buffer (T3 minimum recipe): stage(t+1) before compute(t).
template<int KTOT, int LDB, int LDO, bool BIAS>
__global__ __launch_bounds__(256) void k_mfma_gemm(const unsigned short* __restrict__ A,
                                                   int lda,
                                                   const unsigned short* __restrict__ B,
                                                   const float* __restrict__ bias,
                                                   float* __restrict__ out) {
    __shared__ unsigned short At[2][128 * 32];
    __shared__ unsigned short Bt[2][128 * 32];
    const int m0 = blockIdx.x * 128, n0 = blockIdx.y * 128;
    const int tid = threadIdx.x, wv = tid >> 6, ln = tid & 63;
    const int wr = wv >> 1, wc = wv & 1;
    const int r16 = ln & 15, kg = ln >> 4;
    f32x4 zero = {0.f, 0.f, 0.f, 0.f};
    f32x4 acc[4][4];
    #pragma unroll
    for (int i = 0; i < 4; ++i)
        #pragma unroll
        for (int j = 0; j < 4; ++j) acc[i][j] = zero;

    auto STAGE = [&](int kt, int bsel) {
        #pragma unroll
        for (int i = 0; i < 2; ++i) {
            int e = i * 4096 + wv * 1024 + ln * 16;   // byte offset within 8KB tile
            int row = e >> 6, kb = e & 63;
            const char* ga = (const char*)A + ((size_t)(m0 + row) * lda + kt) * 2 + kb;
            __builtin_amdgcn_global_load_lds(
                (const __attribute__((address_space(1))) void*)ga,
                (__attribute__((address_space(3))) void*)((char*)At[bsel] + i * 4096 + wv * 1024),
                16, 0, 0);
            const char* gb = (const char*)B + ((size_t)(n0 + row) * LDB + kt) * 2 + kb;
            __builtin_amdgcn_global_load_lds(
                (const __attribute__((address_space(1))) void*)gb,
                (__attribute__((address_space(3))) void*)((char*)Bt[bsel] + i * 4096 + wv * 1024),
                16, 0, 0);
        }
    };

    STAGE(0, 0);
    __syncthreads();                 // drains vmcnt: buf0 ready
    int cur = 0;
    for (int kt = 0; kt < KTOT; kt += 32) {
        if (kt + 32 < KTOT) STAGE(kt + 32, cur ^ 1);   // prefetch flies under compute
        short8 af[4], bfr[4];
        #pragma unroll
        for (int i = 0; i < 4; ++i) {
            af[i]  = *(const short8*)&At[cur][(wr * 64 + i * 16 + r16) * 32 + kg * 8];
            bfr[i] = *(const short8*)&Bt[cur][(wc * 64 + i * 16 + r16) * 32 + kg * 8];
        }
        #pragma unroll
        for (int i = 0; i < 4; ++i)
            #pragma unroll
            for (int j = 0; j < 4; ++j)
                acc[i][j] = __builtin_amdgcn_mfma_f32_16x16x32_bf16(af[i], bfr[j], acc[i][j], 0, 0, 0);
        __syncthreads();             // drains vmcnt (t+1 landed) + lgkm; safe to reuse cur next iter
        cur ^= 1;
    }
    // epilogue: C/D layout col=lane&15, row=(lane>>4)*4+reg  [m89/m91]
    #pragma unroll
    for (int j = 0; j < 4; ++j) {
        int col = n0 + wc * 64 + j * 16 + r16;
        float bv = BIAS ? bias[col] : 0.f;
        #pragma unroll
        for (int i = 0; i < 4; ++i) {
            #pragma unroll
            for (int r = 0; r < 4; ++r) {
                int row = m0 + wr * 64 + i * 16 + kg * 4 + r;
                out[(size_t)row * LDO + col] = acc[i][j][r] + bv;
            }
        }
    }
}

extern "C" void kernel_launch(void* const* d_in, const int* in_sizes, int n_in,
                              void* d_out, int out_size, void* d_ws, size_t ws_size,
                              hipStream_t stream) {
    const float* x      = (const float*)d_in[0];
    const float* logLr  = (const float*)d_in[1];
    const float* Li     = (const float*)d_in[2];
    const float* Br     = (const float*)d_in[3];
    const float* Bi     = (const float*)d_in[4];
    const float* Cr     = (const float*)d_in[5];
    const float* Ci     = (const float*)d_in[6];
    const float* Dv     = (const float*)d_in[7];
    const float* log_dt = (const float*)d_in[8];
    const float* W      = (const float*)d_in[9];
    const float* bo     = (const float*)d_in[10];
    float* out = (float*)d_out;
    char*  ws  = (char*)d_ws;

    unsigned short* Abuf = (unsigned short*)(ws + OB_ABUF);
    unsigned short* Bmat = (unsigned short*)(ws + OB_BMAT);
    unsigned short* Bmp  = (unsigned short*)(ws + OB_BMP);
    float* Bu   = (float*)(ws + OB_BU);
    float* Fr   = (float*)(ws + OB_FR);
    float* Fi   = (float*)(ws + OB_FI);
    float* CexR = (float*)(ws + OB_CR);
    float* CexI = (float*)(ws + OB_CI);

    k_prep <<<8768, 256, 0, stream>>>(x, W, Dv, Br, Bi, log_dt, Abuf, Bmat, Bmp);
    k_e2   <<<HD / 4, 256, 0, stream>>>(W, Cr, Ci, Bmat);
    // Bu = x_bf16 @ Bmp^T   (M=16384, N=128, K=1024)
    k_mfma_gemm<1024, 1024, 128, false><<<dim3(MT / 128, 1), 256, 0, stream>>>(Abuf, KA, Bmp, nullptr, Bu);
    k_carry<<<(NB * NS * NCH) / 256, 256, 0, stream>>>(Bu, logLr, Li, log_dt, Fr, Fi);
    k_scan2<<<2, 256, 0, stream>>>(Fr, Fi, logLr, Li, log_dt, CexR, CexI, out + (size_t)MT * HD);
    k_scan3<<<(NB * NS * NCH) / 256, 256, 0, stream>>>(Bu, CexR, CexI, logLr, Li, log_dt, Abuf);
    // out = Abuf @ Bmat^T + bias   (M=16384, N=1024, K=1152)
    k_mfma_gemm<KA, KA, HD, true><<<dim3(MT / 128, HD / 128), 256, 0, stream>>>(Abuf, KA, Bmat, bo, out);
}

// Round 4
// 263.844 us; speedup vs baseline: 1.7143x; 1.7143x over previous
//
#include <hip/hip_runtime.h>

#define HD 1024
#define NS 64
#define NB 8
#define LS 2048
#define MT (NB*LS)        // 16384 rows
#define N2 128            // 2*NS
#define KA 1152           // HD + N2, A/B leading dim (K-extended)
#define CHL 16            // scan chunk length
#define NCH (LS/CHL)      // 128 chunks

typedef __attribute__((ext_vector_type(8))) short short8;
typedef __attribute__((ext_vector_type(4))) float f32x4;

// ---- workspace byte offsets -------------------------------------------------
#define OB_ABUF 0u                               // bf16 [16384][1152]
#define OB_BMAT (OB_ABUF + MT*KA*2)              // bf16 [1024][1152]
#define OB_BMP  (OB_BMAT + HD*KA*2)              // bf16 [128][1024]
#define OB_BU   (OB_BMP  + N2*HD*2)              // f32  [16384][128]
#define OB_FR   (OB_BU   + MT*N2*4)              // f32  [8*64*128]
#define OB_FI   (OB_FR   + NB*NS*NCH*4)
#define OB_CR   (OB_FI   + NB*NS*NCH*4)
#define OB_CI   (OB_CR   + NB*NS*NCH*4)
#define OB_WB   (OB_CI   + NB*NS*NCH*4)          // bf16 [1024][1024] raw W
#define OB_CCT  (OB_WB   + HD*HD*2)              // bf16 [128][1024]  CC^T
// end ~ 52.4 MB

__device__ __forceinline__ unsigned short f2bf(float f) {
    unsigned u = __float_as_uint(f);
    u = (u + 0x7FFFu + ((u >> 16) & 1u)) >> 16;
    return (unsigned short)u;
}

__device__ __forceinline__ void lbar_of(int n, const float* __restrict__ logLr,
                                        const float* __restrict__ Li, float dt,
                                        float& ar, float& ai) {
    float lr  = -expf(logLr[n]);
    float mag = expf(lr * dt);
    float ang = Li[n] * dt;
    ar = mag * cosf(ang);
    ai = mag * sinf(ang);
}

// ---------------- fused prep: cast x / D*W / dt*B / raw W -------------------
// blocks [0,8192): Abuf cols 0..1023 = bf16(x)
// blocks [8192,8704): Bmat cols 0..1023 = bf16(D[k]*W[h,k])
// blocks [8704,8768): Bmp[n2][k] = bf16(dt*(Br|Bi))
// blocks [8768,9280): Wb[h][k] = bf16(W[h,k])
__global__ __launch_bounds__(256) void k_prep(const float* __restrict__ x,
                                              const float* __restrict__ W,
                                              const float* __restrict__ Dv,
                                              const float* __restrict__ Br,
                                              const float* __restrict__ Bi,
                                              const float* __restrict__ log_dt,
                                              unsigned short* __restrict__ Ab,
                                              unsigned short* __restrict__ Bm,
                                              unsigned short* __restrict__ Bp,
                                              unsigned short* __restrict__ Wb) {
    const int blk = blockIdx.x;
    if (blk < 8192) {
        size_t idx = ((size_t)blk * 256 + threadIdx.x) * 8;
        int m = (int)(idx >> 10), k = (int)(idx & 1023);
        float4 v0 = *(const float4*)&x[idx];
        float4 v1 = *(const float4*)&x[idx + 4];
        short8 s;
        s[0]=f2bf(v0.x); s[1]=f2bf(v0.y); s[2]=f2bf(v0.z); s[3]=f2bf(v0.w);
        s[4]=f2bf(v1.x); s[5]=f2bf(v1.y); s[6]=f2bf(v1.z); s[7]=f2bf(v1.w);
        *(short8*)&Ab[(size_t)m * KA + k] = s;
    } else if (blk < 8704) {
        size_t idx = ((size_t)(blk - 8192) * 256 + threadIdx.x) * 8;
        int h = (int)(idx >> 10), k = (int)(idx & 1023);
        float4 v0 = *(const float4*)&W[idx];
        float4 v1 = *(const float4*)&W[idx + 4];
        float4 d0 = *(const float4*)&Dv[k];
        float4 d1 = *(const float4*)&Dv[k + 4];
        short8 s;
        s[0]=f2bf(v0.x*d0.x); s[1]=f2bf(v0.y*d0.y); s[2]=f2bf(v0.z*d0.z); s[3]=f2bf(v0.w*d0.w);
        s[4]=f2bf(v1.x*d1.x); s[5]=f2bf(v1.y*d1.y); s[6]=f2bf(v1.z*d1.z); s[7]=f2bf(v1.w*d1.w);
        *(short8*)&Bm[(size_t)h * KA + k] = s;
    } else if (blk < 8768) {
        size_t idx = ((size_t)(blk - 8704) * 256 + threadIdx.x) * 8;
        int n2 = (int)(idx >> 10), k = (int)(idx & 1023);
        float dt = expf(log_dt[0]);
        const float* src = (n2 < NS) ? &Br[(size_t)n2 * HD + k] : &Bi[(size_t)(n2 - NS) * HD + k];
        float4 v0 = *(const float4*)&src[0];
        float4 v1 = *(const float4*)&src[4];
        short8 s;
        s[0]=f2bf(v0.x*dt); s[1]=f2bf(v0.y*dt); s[2]=f2bf(v0.z*dt); s[3]=f2bf(v0.w*dt);
        s[4]=f2bf(v1.x*dt); s[5]=f2bf(v1.y*dt); s[6]=f2bf(v1.z*dt); s[7]=f2bf(v1.w*dt);
        *(short8*)&Bp[(size_t)n2 * HD + k] = s;
    } else {
        size_t idx = ((size_t)(blk - 8768) * 256 + threadIdx.x) * 8;
        float4 v0 = *(const float4*)&W[idx];
        float4 v1 = *(const float4*)&W[idx + 4];
        short8 s;
        s[0]=f2bf(v0.x); s[1]=f2bf(v0.y); s[2]=f2bf(v0.z); s[3]=f2bf(v0.w);
        s[4]=f2bf(v1.x); s[5]=f2bf(v1.y); s[6]=f2bf(v1.z); s[7]=f2bf(v1.w);
        *(short8*)&Wb[idx] = s;
    }
}

// ---------------- transpose-cast: CCT[n2][h] = bf16(±C[h][n2]) --------------
// grid (16 h-tiles, 2 halves). LDS 64x65 fp32 tile.
__global__ __launch_bounds__(256) void k_tcc(const float* __restrict__ Cr,
                                             const float* __restrict__ Ci,
                                             unsigned short* __restrict__ CCT) {
    __shared__ float T[64][65];
    const int h0 = blockIdx.x * 64;
    const int half = blockIdx.y;          // 0: Cr, 1: -Ci
    const float* src = half ? Ci : Cr;
    const float sgn = half ? -1.f : 1.f;
    const int tid = threadIdx.x;
    const int j = tid & 63, i4 = tid >> 6;
    #pragma unroll
    for (int p = 0; p < 16; ++p) {
        int i = p * 4 + i4;
        T[i][j] = src[(size_t)(h0 + i) * NS + j];
    }
    __syncthreads();
    #pragma unroll
    for (int p = 0; p < 16; ++p) {
        int jj = p * 4 + i4;              // n within half
        CCT[(size_t)(half * NS + jj) * HD + h0 + j] = f2bf(sgn * T[j][jj]);
    }
}

// ---------------- scan pass A: per-chunk carry-out (from zero state) --------
__global__ __launch_bounds__(256) void k_carry(const float* __restrict__ Bu,
                                               const float* __restrict__ logLr,
                                               const float* __restrict__ Li,
                                               const float* __restrict__ log_dt,
                                               float* __restrict__ Fr,
                                               float* __restrict__ Fi) {
    int g = blockIdx.x * 256 + threadIdx.x;       // 65536 = 8b * 128ch * 64n
    int n = g & 63, ch = (g >> 6) & (NCH - 1), b = g >> 13;
    float dt = expf(log_dt[0]);
    float ar, ai; lbar_of(n, logLr, Li, dt, ar, ai);
    float sr = 0.f, si = 0.f;
    size_t base = ((size_t)b * LS + ch * CHL) * N2;
    #pragma unroll 4
    for (int j = 0; j < CHL; ++j) {
        float ur = Bu[base + j * N2 + n];
        float ui = Bu[base + j * N2 + NS + n];
        float nr = ar * sr - ai * si + ur;
        float ni = ar * si + ai * sr + ui;
        sr = nr; si = ni;
    }
    int fi = (b * NS + n) * NCH + ch;
    Fr[fi] = sr; Fi[fi] = si;
}

// ---------------- scan pass B: carry scan + final states --------------------
__global__ __launch_bounds__(256) void k_scan2(const float* __restrict__ Fr,
                                               const float* __restrict__ Fi,
                                               const float* __restrict__ logLr,
                                               const float* __restrict__ Li,
                                               const float* __restrict__ log_dt,
                                               float* __restrict__ CexR,
                                               float* __restrict__ CexI,
                                               float* __restrict__ out_tail) {
    int g = blockIdx.x * 256 + threadIdx.x;       // 512 = 8b * 64n
    if (g >= NB * NS) return;
    int n = g & 63;
    float dt = expf(log_dt[0]);
    float ar, ai; lbar_of(n, logLr, Li, dt, ar, ai);
    float Ar = ar, Ai = ai;                        // a^16 via 4 squarings
    #pragma unroll
    for (int s = 0; s < 4; ++s) { float nr = Ar*Ar - Ai*Ai; Ai = 2.f*Ar*Ai; Ar = nr; }
    float cr = 0.f, ci = 0.f;
    for (int ch = 0; ch < NCH; ++ch) {
        CexR[g * NCH + ch] = cr; CexI[g * NCH + ch] = ci;
        float fr = Fr[g * NCH + ch], fi2 = Fi[g * NCH + ch];
        float nr = Ar * cr - Ai * ci + fr;
        float ni = Ar * ci + Ai * cr + fi2;
        cr = nr; ci = ni;
    }
    out_tail[g]          = cr;    // sr final (B,N)
    out_tail[NB*NS + g]  = ci;    // si final
}

// ---------------- scan pass C: replay with carry, write bf16 S into Abuf ----
__global__ __launch_bounds__(256) void k_scan3(const float* __restrict__ Bu,
                                               const float* __restrict__ CexR,
                                               const float* __restrict__ CexI,
                                               const float* __restrict__ logLr,
                                               const float* __restrict__ Li,
                                               const float* __restrict__ log_dt,
                                               unsigned short* __restrict__ Ab) {
    int g = blockIdx.x * 256 + threadIdx.x;
    int n = g & 63, ch = (g >> 6) & (NCH - 1), b = g >> 13;
    float dt = expf(log_dt[0]);
    float ar, ai; lbar_of(n, logLr, Li, dt, ar, ai);
    int ci_idx = (b * NS + n) * NCH + ch;
    float sr = CexR[ci_idx], si = CexI[ci_idx];
    size_t base = ((size_t)b * LS + ch * CHL);
    #pragma unroll 4
    for (int j = 0; j < CHL; ++j) {
        size_t m = base + j;
        float ur = Bu[m * N2 + n];
        float ui = Bu[m * N2 + NS + n];
        float nr = ar * sr - ai * si + ur;
        float ni = ar * si + ai * sr + ui;
        sr = nr; si = ni;
        Ab[m * KA + HD + n]      = f2bf(sr);
        Ab[m * KA + HD + NS + n] = f2bf(si);
    }
}

// ---------------- MFMA GEMM: out[M,N] = A[M,K] * B[N,K]^T (+bias) -----------
// Round-2 proven structure: 128x128 tile, BK=32, 4 waves (2x2),
// global_load_lds w=16, single-buffered.
template<int KTOT, int LDB, int LDO, bool BIAS, bool BF16OUT>
__global__ __launch_bounds__(256) void k_mfma_gemm(const unsigned short* __restrict__ A,
                                                   int lda,
                                                   const unsigned short* __restrict__ B,
                                                   const float* __restrict__ bias,
                                                   void* __restrict__ outp) {
    __shared__ unsigned short At[128 * 32];
    __shared__ unsigned short Bt[128 * 32];
    const int m0 = blockIdx.x * 128, n0 = blockIdx.y * 128;
    const int tid = threadIdx.x, wv = tid >> 6, ln = tid & 63;
    const int wr = wv >> 1, wc = wv & 1;
    const int r16 = ln & 15, kg = ln >> 4;
    f32x4 zero = {0.f, 0.f, 0.f, 0.f};
    f32x4 acc[4][4];
    #pragma unroll
    for (int i = 0; i < 4; ++i)
        #pragma unroll
        for (int j = 0; j < 4; ++j) acc[i][j] = zero;

    for (int kt = 0; kt < KTOT; kt += 32) {
        #pragma unroll
        for (int i = 0; i < 2; ++i) {
            int e = i * 4096 + wv * 1024 + ln * 16;   // byte offset within 8KB tile
            int row = e >> 6, kb = e & 63;
            const char* ga = (const char*)A + ((size_t)(m0 + row) * lda + kt) * 2 + kb;
            __builtin_amdgcn_global_load_lds(
                (const __attribute__((address_space(1))) void*)ga,
                (__attribute__((address_space(3))) void*)((char*)At + i * 4096 + wv * 1024),
                16, 0, 0);
            const char* gb = (const char*)B + ((size_t)(n0 + row) * LDB + kt) * 2 + kb;
            __builtin_amdgcn_global_load_lds(
                (const __attribute__((address_space(1))) void*)gb,
                (__attribute__((address_space(3))) void*)((char*)Bt + i * 4096 + wv * 1024),
                16, 0, 0);
        }
        __syncthreads();
        short8 af[4], bfr[4];
        #pragma unroll
        for (int i = 0; i < 4; ++i) {
            af[i]  = *(const short8*)&At[(wr * 64 + i * 16 + r16) * 32 + kg * 8];
            bfr[i] = *(const short8*)&Bt[(wc * 64 + i * 16 + r16) * 32 + kg * 8];
        }
        #pragma unroll
        for (int i = 0; i < 4; ++i)
            #pragma unroll
            for (int j = 0; j < 4; ++j)
                acc[i][j] = __builtin_amdgcn_mfma_f32_16x16x32_bf16(af[i], bfr[j], acc[i][j], 0, 0, 0);
        __syncthreads();
    }
    // epilogue: C/D layout col=lane&15, row=(lane>>4)*4+reg  [m89/m91]
    #pragma unroll
    for (int j = 0; j < 4; ++j) {
        int col = n0 + wc * 64 + j * 16 + r16;
        float bv = BIAS ? bias[col] : 0.f;
        #pragma unroll
        for (int i = 0; i < 4; ++i) {
            #pragma unroll
            for (int r = 0; r < 4; ++r) {
                int row = m0 + wr * 64 + i * 16 + kg * 4 + r;
                if (BF16OUT) ((unsigned short*)outp)[(size_t)row * LDO + col] = f2bf(acc[i][j][r] + bv);
                else         ((float*)outp)[(size_t)row * LDO + col] = acc[i][j][r] + bv;
            }
        }
    }
}

extern "C" void kernel_launch(void* const* d_in, const int* in_sizes, int n_in,
                              void* d_out, int out_size, void* d_ws, size_t ws_size,
                              hipStream_t stream) {
    const float* x      = (const float*)d_in[0];
    const float* logLr  = (const float*)d_in[1];
    const float* Li     = (const float*)d_in[2];
    const float* Br     = (const float*)d_in[3];
    const float* Bi     = (const float*)d_in[4];
    const float* Cr     = (const float*)d_in[5];
    const float* Ci     = (const float*)d_in[6];
    const float* Dv     = (const float*)d_in[7];
    const float* log_dt = (const float*)d_in[8];
    const float* W      = (const float*)d_in[9];
    const float* bo     = (const float*)d_in[10];
    float* out = (float*)d_out;
    char*  ws  = (char*)d_ws;

    unsigned short* Abuf = (unsigned short*)(ws + OB_ABUF);
    unsigned short* Bmat = (unsigned short*)(ws + OB_BMAT);
    unsigned short* Bmp  = (unsigned short*)(ws + OB_BMP);
    float* Bu   = (float*)(ws + OB_BU);
    float* Fr   = (float*)(ws + OB_FR);
    float* Fi   = (float*)(ws + OB_FI);
    float* CexR = (float*)(ws + OB_CR);
    float* CexI = (float*)(ws + OB_CI);
    unsigned short* Wb   = (unsigned short*)(ws + OB_WB);
    unsigned short* CCT  = (unsigned short*)(ws + OB_CCT);

    k_prep <<<9280, 256, 0, stream>>>(x, W, Dv, Br, Bi, log_dt, Abuf, Bmat, Bmp, Wb);
    k_tcc  <<<dim3(16, 2), 256, 0, stream>>>(Cr, Ci, CCT);
    // E2T (into Bmat cols 1024..1151) = Wb @ CCT^T  (M=1024, N=128, K=1024)
    k_mfma_gemm<1024, 1024, KA, false, true><<<dim3(HD / 128, 1), 256, 0, stream>>>(
        Wb, HD, CCT, nullptr, Bmat + HD);
    // Bu = x_bf16 @ Bmp^T   (M=16384, N=128, K=1024)
    k_mfma_gemm<1024, 1024, 128, false, false><<<dim3(MT / 128, 1), 256, 0, stream>>>(
        Abuf, KA, Bmp, nullptr, Bu);
    k_carry<<<(NB * NS * NCH) / 256, 256, 0, stream>>>(Bu, logLr, Li, log_dt, Fr, Fi);
    k_scan2<<<2, 256, 0, stream>>>(Fr, Fi, logLr, Li, log_dt, CexR, CexI, out + (size_t)MT * HD);
    k_scan3<<<(NB * NS * NCH) / 256, 256, 0, stream>>>(Bu, CexR, CexI, logLr, Li, log_dt, Abuf);
    // out = Abuf @ Bmat^T + bias   (M=16384, N=1024, K=1152)
    k_mfma_gemm<KA, KA, HD, true, false><<<dim3(MT / 128, HD / 128), 256, 0, stream>>>(
        Abuf, KA, Bmat, bo, out);
}

// Round 5
// 234.047 us; speedup vs baseline: 1.9325x; 1.1273x over previous
//
#include <hip/hip_runtime.h>

#define HD 1024
#define NS 64
#define NB 8
#define LS 2048
#define MT (NB*LS)        // 16384 rows
#define N2 128            // 2*NS
#define KA 1152           // HD + N2, A leading dim (K-extended)
#define CHL 16            // scan chunk length
#define NCH (LS/CHL)      // 128 chunks
#define NG  (NB*NS)       // 512 scan chains

typedef __attribute__((ext_vector_type(8))) short short8;
typedef __attribute__((ext_vector_type(4))) float f32x4;

// ---- workspace byte offsets -------------------------------------------------
#define OB_ABUF 0u                               // bf16 [16384][1152]
#define OB_BMAT (OB_ABUF + MT*KA*2)              // bf16 [1024][1152]
#define OB_BMP  (OB_BMAT + HD*KA*2)              // bf16 [128][1024]
#define OB_BU   (OB_BMP  + N2*HD*2)              // f32  [16384][128]
#define OB_FR   (OB_BU   + MT*N2*4)              // f32  [NCH][NG]
#define OB_FI   (OB_FR   + NG*NCH*4)
#define OB_CR   (OB_FI   + NG*NCH*4)
#define OB_CI   (OB_CR   + NG*NCH*4)
#define OB_WB   (OB_CI   + NG*NCH*4)             // bf16 [1024][1024] raw W
#define OB_CCT  (OB_WB   + HD*HD*2)              // bf16 [128][1024]  CC^T
// end ~ 52.4 MB

__device__ __forceinline__ unsigned short f2bf(float f) {
    unsigned u = __float_as_uint(f);
    u = (u + 0x7FFFu + ((u >> 16) & 1u)) >> 16;
    return (unsigned short)u;
}

__device__ __forceinline__ void lbar_of(int n, const float* __restrict__ logLr,
                                        const float* __restrict__ Li, float dt,
                                        float& ar, float& ai) {
    float lr  = -expf(logLr[n]);
    float mag = expf(lr * dt);
    float ang = Li[n] * dt;
    ar = mag * cosf(ang);
    ai = mag * sinf(ang);
}

// ---------------- fused prep: cast x / D*W / dt*B / raw W / CC^T ------------
// blocks [0,8192): Abuf cols 0..1023 = bf16(x)
// blocks [8192,8704): Bmat cols 0..1023 = bf16(D[k]*W[h,k])
// blocks [8704,8768): Bmp[n2][k] = bf16(dt*(Br|Bi))
// blocks [8768,9280): Wb[h][k] = bf16(W[h,k])
// blocks [9280,9312): CCT[n2][h] = bf16(+/-C[h][n2])  (transpose-cast)
__global__ __launch_bounds__(256) void k_prep(const float* __restrict__ x,
                                              const float* __restrict__ W,
                                              const float* __restrict__ Dv,
                                              const float* __restrict__ Br,
                                              const float* __restrict__ Bi,
                                              const float* __restrict__ Cr,
                                              const float* __restrict__ Ci,
                                              const float* __restrict__ log_dt,
                                              unsigned short* __restrict__ Ab,
                                              unsigned short* __restrict__ Bm,
                                              unsigned short* __restrict__ Bp,
                                              unsigned short* __restrict__ Wb,
                                              unsigned short* __restrict__ CCT) {
    __shared__ float T[64][65];
    const int blk = blockIdx.x;
    if (blk < 8192) {
        size_t idx = ((size_t)blk * 256 + threadIdx.x) * 8;
        int m = (int)(idx >> 10), k = (int)(idx & 1023);
        float4 v0 = *(const float4*)&x[idx];
        float4 v1 = *(const float4*)&x[idx + 4];
        short8 s;
        s[0]=f2bf(v0.x); s[1]=f2bf(v0.y); s[2]=f2bf(v0.z); s[3]=f2bf(v0.w);
        s[4]=f2bf(v1.x); s[5]=f2bf(v1.y); s[6]=f2bf(v1.z); s[7]=f2bf(v1.w);
        *(short8*)&Ab[(size_t)m * KA + k] = s;
    } else if (blk < 8704) {
        size_t idx = ((size_t)(blk - 8192) * 256 + threadIdx.x) * 8;
        int h = (int)(idx >> 10), k = (int)(idx & 1023);
        float4 v0 = *(const float4*)&W[idx];
        float4 v1 = *(const float4*)&W[idx + 4];
        float4 d0 = *(const float4*)&Dv[k];
        float4 d1 = *(const float4*)&Dv[k + 4];
        short8 s;
        s[0]=f2bf(v0.x*d0.x); s[1]=f2bf(v0.y*d0.y); s[2]=f2bf(v0.z*d0.z); s[3]=f2bf(v0.w*d0.w);
        s[4]=f2bf(v1.x*d1.x); s[5]=f2bf(v1.y*d1.y); s[6]=f2bf(v1.z*d1.z); s[7]=f2bf(v1.w*d1.w);
        *(short8*)&Bm[(size_t)h * KA + k] = s;
    } else if (blk < 8768) {
        size_t idx = ((size_t)(blk - 8704) * 256 + threadIdx.x) * 8;
        int n2 = (int)(idx >> 10), k = (int)(idx & 1023);
        float dt = expf(log_dt[0]);
        const float* src = (n2 < NS) ? &Br[(size_t)n2 * HD + k] : &Bi[(size_t)(n2 - NS) * HD + k];
        float4 v0 = *(const float4*)&src[0];
        float4 v1 = *(const float4*)&src[4];
        short8 s;
        s[0]=f2bf(v0.x*dt); s[1]=f2bf(v0.y*dt); s[2]=f2bf(v0.z*dt); s[3]=f2bf(v0.w*dt);
        s[4]=f2bf(v1.x*dt); s[5]=f2bf(v1.y*dt); s[6]=f2bf(v1.z*dt); s[7]=f2bf(v1.w*dt);
        *(short8*)&Bp[(size_t)n2 * HD + k] = s;
    } else if (blk < 9280) {
        size_t idx = ((size_t)(blk - 8768) * 256 + threadIdx.x) * 8;
        float4 v0 = *(const float4*)&W[idx];
        float4 v1 = *(const float4*)&W[idx + 4];
        short8 s;
        s[0]=f2bf(v0.x); s[1]=f2bf(v0.y); s[2]=f2bf(v0.z); s[3]=f2bf(v0.w);
        s[4]=f2bf(v1.x); s[5]=f2bf(v1.y); s[6]=f2bf(v1.z); s[7]=f2bf(v1.w);
        *(short8*)&Wb[idx] = s;
    } else {
        const int local = blk - 9280;
        const int h0 = (local & 15) * 64;
        const int half = local >> 4;          // 0: Cr, 1: -Ci
        const float* src = half ? Ci : Cr;
        const float sgn = half ? -1.f : 1.f;
        const int tid = threadIdx.x;
        const int j = tid & 63, i4 = tid >> 6;
        #pragma unroll
        for (int p = 0; p < 16; ++p) {
            int i = p * 4 + i4;
            T[i][j] = src[(size_t)(h0 + i) * NS + j];
        }
        __syncthreads();
        #pragma unroll
        for (int p = 0; p < 16; ++p) {
            int jj = p * 4 + i4;              // n within half
            CCT[(size_t)(half * NS + jj) * HD + h0 + j] = f2bf(sgn * T[j][jj]);
        }
    }
}

// ---------------- scan pass A: per-chunk carry-out (from zero state) --------
// F layout: [ch][g]  (g = b*64+n)  -> coalesced writes here, coalesced reads in scan2
__global__ __launch_bounds__(256) void k_carry(const float* __restrict__ Bu,
                                               const float* __restrict__ logLr,
                                               const float* __restrict__ Li,
                                               const float* __restrict__ log_dt,
                                               float* __restrict__ Fr,
                                               float* __restrict__ Fi) {
    int g = blockIdx.x * 256 + threadIdx.x;       // 65536 = 8b * 128ch * 64n
    int n = g & 63, ch = (g >> 6) & (NCH - 1), b = g >> 13;
    float dt = expf(log_dt[0]);
    float ar, ai; lbar_of(n, logLr, Li, dt, ar, ai);
    float sr = 0.f, si = 0.f;
    size_t base = ((size_t)b * LS + ch * CHL) * N2;
    #pragma unroll 4
    for (int j = 0; j < CHL; ++j) {
        float ur = Bu[base + j * N2 + n];
        float ui = Bu[base + j * N2 + NS + n];
        float nr = ar * sr - ai * si + ur;
        float ni = ar * si + ai * sr + ui;
        sr = nr; si = ni;
    }
    int fi = ch * NG + b * 64 + n;
    Fr[fi] = sr; Fi[fi] = si;
}

// ---------------- scan pass B: carry scan + final states --------------------
__global__ __launch_bounds__(256) void k_scan2(const float* __restrict__ Fr,
                                               const float* __restrict__ Fi,
                                               const float* __restrict__ logLr,
                                               const float* __restrict__ Li,
                                               const float* __restrict__ log_dt,
                                               float* __restrict__ CexR,
                                               float* __restrict__ CexI,
                                               float* __restrict__ out_tail) {
    int g = blockIdx.x * 256 + threadIdx.x;       // 512 = 8b * 64n
    if (g >= NG) return;
    int n = g & 63;
    float dt = expf(log_dt[0]);
    float ar, ai; lbar_of(n, logLr, Li, dt, ar, ai);
    float Ar = ar, Ai = ai;                        // a^16 via 4 squarings
    #pragma unroll
    for (int s = 0; s < 4; ++s) { float nr = Ar*Ar - Ai*Ai; Ai = 2.f*Ar*Ai; Ar = nr; }
    float cr = 0.f, ci = 0.f;
    for (int ch = 0; ch < NCH; ++ch) {
        CexR[ch * NG + g] = cr; CexI[ch * NG + g] = ci;
        float fr = Fr[ch * NG + g], fi2 = Fi[ch * NG + g];
        float nr = Ar * cr - Ai * ci + fr;
        float ni = Ar * ci + Ai * cr + fi2;
        cr = nr; ci = ni;
    }
    out_tail[g]       = cr;    // sr final (B,N)
    out_tail[NG + g]  = ci;    // si final
}

// ---------------- scan pass C: replay with carry, write bf16 S into Abuf ----
__global__ __launch_bounds__(256) void k_scan3(const float* __restrict__ Bu,
                                               const float* __restrict__ CexR,
                                               const float* __restrict__ CexI,
                                               const float* __restrict__ logLr,
                                               const float* __restrict__ Li,
                                               const float* __restrict__ log_dt,
                                               unsigned short* __restrict__ Ab) {
    int g = blockIdx.x * 256 + threadIdx.x;
    int n = g & 63, ch = (g >> 6) & (NCH - 1), b = g >> 13;
    float dt = expf(log_dt[0]);
    float ar, ai; lbar_of(n, logLr, Li, dt, ar, ai);
    int ci_idx = ch * NG + b * 64 + n;
    float sr = CexR[ci_idx], si = CexI[ci_idx];
    size_t base = ((size_t)b * LS + ch * CHL);
    #pragma unroll 4
    for (int j = 0; j < CHL; ++j) {
        size_t m = base + j;
        float ur = Bu[m * N2 + n];
        float ui = Bu[m * N2 + NS + n];
        float nr = ar * sr - ai * si + ur;
        float ni = ar * si + ai * sr + ui;
        sr = nr; si = ni;
        Ab[m * KA + HD + n]      = f2bf(sr);
        Ab[m * KA + HD + NS + n] = f2bf(si);
    }
}

// ---------------- unified MFMA GEMM body ------------------------------------
// out[M,N] = A[M,K] * B[N,K]^T (+bias). 128x128 tile, BK=32, 4 waves (2x2),
// global_load_lds w=16, 3-deep ring pipeline with counted vmcnt (T4):
// per iter: wait vmcnt(tiles-in-flight*4) -> s_barrier -> ds_read+MFMA ->
// s_barrier -> STAGE(t+3). Never vmcnt(0) in steady state.
template<int KTOT>
__device__ __forceinline__ void gemm_body(const unsigned short* __restrict__ A, int lda,
                                          const unsigned short* __restrict__ B, int ldb,
                                          const float* __restrict__ bias, int has_bias,
                                          void* __restrict__ outp, int ldo, int bf16out,
                                          int m0, int n0) {
    constexpr int T = KTOT / 32;
    __shared__ unsigned short At[3][128 * 32];
    __shared__ unsigned short Bt[3][128 * 32];
    const int tid = threadIdx.x, wv = tid >> 6, ln = tid & 63;
    const int wr = wv >> 1, wc = wv & 1;
    const int r16 = ln & 15, kg = ln >> 4;
    f32x4 zero = {0.f, 0.f, 0.f, 0.f};
    f32x4 acc[4][4];
    #pragma unroll
    for (int i = 0; i < 4; ++i)
        #pragma unroll
        for (int j = 0; j < 4; ++j) acc[i][j] = zero;

    auto STAGE = [&](int t, int s) {
        const int kt = t * 32;
        #pragma unroll
        for (int i = 0; i < 2; ++i) {
            int e = i * 4096 + wv * 1024 + ln * 16;   // byte offset within 8KB tile
            int row = e >> 6, kb = e & 63;
            const char* ga = (const char*)A + ((size_t)(m0 + row) * lda + kt) * 2 + kb;
            __builtin_amdgcn_global_load_lds(
                (const __attribute__((address_space(1))) void*)ga,
                (__attribute__((address_space(3))) void*)((char*)At[s] + i * 4096 + wv * 1024),
                16, 0, 0);
            const char* gb = (const char*)B + ((size_t)(n0 + row) * ldb + kt) * 2 + kb;
            __builtin_amdgcn_global_load_lds(
                (const __attribute__((address_space(1))) void*)gb,
                (__attribute__((address_space(3))) void*)((char*)Bt[s] + i * 4096 + wv * 1024),
                16, 0, 0);
        }
    };

    STAGE(0, 0); STAGE(1, 1); STAGE(2, 2);   // 12 loads/thread in flight
    int s = 0;
    for (int t = 0; t < T; ++t) {
        // per-wave counted wait for tile t's own 4 loads, then block-wide barrier
        if (t + 2 < T)      asm volatile("s_waitcnt vmcnt(8)" ::: "memory");
        else if (t + 1 < T) asm volatile("s_waitcnt vmcnt(4)" ::: "memory");
        else                asm volatile("s_waitcnt vmcnt(0)" ::: "memory");
        __builtin_amdgcn_s_barrier();
        asm volatile("" ::: "memory");
        short8 af[4], bfr[4];
        #pragma unroll
        for (int i = 0; i < 4; ++i) {
            af[i]  = *(const short8*)&At[s][(wr * 64 + i * 16 + r16) * 32 + kg * 8];
            bfr[i] = *(const short8*)&Bt[s][(wc * 64 + i * 16 + r16) * 32 + kg * 8];
        }
        __builtin_amdgcn_s_setprio(1);
        #pragma unroll
        for (int i = 0; i < 4; ++i)
            #pragma unroll
            for (int j = 0; j < 4; ++j)
                acc[i][j] = __builtin_amdgcn_mfma_f32_16x16x32_bf16(af[i], bfr[j], acc[i][j], 0, 0, 0);
        __builtin_amdgcn_s_setprio(0);
        asm volatile("" ::: "memory");
        __builtin_amdgcn_s_barrier();     // all waves done reading buf s
        if (t + 3 < T) STAGE(t + 3, s);   // overwrite buf s with tile t+3
        if (++s == 3) s = 0;
    }
    // epilogue: C/D layout col=lane&15, row=(lane>>4)*4+reg  [m89/m91]
    #pragma unroll
    for (int j = 0; j < 4; ++j) {
        int col = n0 + wc * 64 + j * 16 + r16;
        float bv = has_bias ? bias[col] : 0.f;
        #pragma unroll
        for (int i = 0; i < 4; ++i) {
            #pragma unroll
            for (int r = 0; r < 4; ++r) {
                int row = m0 + wr * 64 + i * 16 + kg * 4 + r;
                if (bf16out) ((unsigned short*)outp)[(size_t)row * ldo + col] = f2bf(acc[i][j][r] + bv);
                else         ((float*)outp)[(size_t)row * ldo + col] = acc[i][j][r] + bv;
            }
        }
    }
}

// big GEMM: out = Abuf @ Bmat^T + bias   (M=16384, N=1024, K=1152)
__global__ __launch_bounds__(256) void k_gemm_big(const unsigned short* __restrict__ A,
                                                  const unsigned short* __restrict__ B,
                                                  const float* __restrict__ bias,
                                                  float* __restrict__ out) {
    gemm_body<KA>(A, KA, B, KA, bias, 1, out, HD, 0, blockIdx.x * 128, blockIdx.y * 128);
}

// fused small GEMMs (N=128, K=1024):
// blocks [0,128):  Bu = Abuf @ Bmp^T           (f32 out, ldo=128)
// blocks [128,136): E2T = Wb @ CCT^T -> Bmat+HD (bf16 out, ldo=KA)
__global__ __launch_bounds__(256) void k_gemm_small(const unsigned short* __restrict__ Abuf,
                                                    const unsigned short* __restrict__ Bmp,
                                                    const unsigned short* __restrict__ Wb,
                                                    const unsigned short* __restrict__ CCT,
                                                    float* __restrict__ Bu,
                                                    unsigned short* __restrict__ BmE2) {
    const int bx = blockIdx.x;
    if (bx < 128) {
        gemm_body<1024>(Abuf, KA, Bmp, 1024, nullptr, 0, Bu, 128, 0, bx * 128, 0);
    } else {
        gemm_body<1024>(Wb, 1024, CCT, 1024, nullptr, 0, BmE2, KA, 1, (bx - 128) * 128, 0);
    }
}

extern "C" void kernel_launch(void* const* d_in, const int* in_sizes, int n_in,
                              void* d_out, int out_size, void* d_ws, size_t ws_size,
                              hipStream_t stream) {
    const float* x      = (const float*)d_in[0];
    const float* logLr  = (const float*)d_in[1];
    const float* Li     = (const float*)d_in[2];
    const float* Br     = (const float*)d_in[3];
    const float* Bi     = (const float*)d_in[4];
    const float* Cr     = (const float*)d_in[5];
    const float* Ci     = (const float*)d_in[6];
    const float* Dv     = (const float*)d_in[7];
    const float* log_dt = (const float*)d_in[8];
    const float* W      = (const float*)d_in[9];
    const float* bo     = (const float*)d_in[10];
    float* out = (float*)d_out;
    char*  ws  = (char*)d_ws;

    unsigned short* Abuf = (unsigned short*)(ws + OB_ABUF);
    unsigned short* Bmat = (unsigned short*)(ws + OB_BMAT);
    unsigned short* Bmp  = (unsigned short*)(ws + OB_BMP);
    float* Bu   = (float*)(ws + OB_BU);
    float* Fr   = (float*)(ws + OB_FR);
    float* Fi   = (float*)(ws + OB_FI);
    float* CexR = (float*)(ws + OB_CR);
    float* CexI = (float*)(ws + OB_CI);
    unsigned short* Wb   = (unsigned short*)(ws + OB_WB);
    unsigned short* CCT  = (unsigned short*)(ws + OB_CCT);

    k_prep <<<9312, 256, 0, stream>>>(x, W, Dv, Br, Bi, Cr, Ci, log_dt, Abuf, Bmat, Bmp, Wb, CCT);
    k_gemm_small<<<136, 256, 0, stream>>>(Abuf, Bmp, Wb, CCT, Bu, Bmat + HD);
    k_carry<<<(NB * NS * NCH) / 256, 256, 0, stream>>>(Bu, logLr, Li, log_dt, Fr, Fi);
    k_scan2<<<2, 256, 0, stream>>>(Fr, Fi, logLr, Li, log_dt, CexR, CexI, out + (size_t)MT * HD);
    k_scan3<<<(NB * NS * NCH) / 256, 256, 0, stream>>>(Bu, CexR, CexI, logLr, Li, log_dt, Abuf);
    k_gemm_big<<<dim3(MT / 128, HD / 128), 256, 0, stream>>>(Abuf, Bmat, bo, out);
}

// Round 6
// 230.033 us; speedup vs baseline: 1.9663x; 1.0175x over previous
//
#include <hip/hip_runtime.h>

#define HD 1024
#define NS 64
#define NB 8
#define LS 2048
#define MT (NB*LS)        // 16384 rows
#define N2 128            // 2*NS
#define KA 1152           // HD + N2, A leading dim (K-extended)
#define CHL 16            // scan chunk length
#define NCH (LS/CHL)      // 128 chunks
#define NG  (NB*NS)       // 512 scan chains

typedef __attribute__((ext_vector_type(8))) short short8;
typedef __attribute__((ext_vector_type(4))) float f32x4;

// ---- workspace byte offsets -------------------------------------------------
#define OB_ABUF 0u                               // bf16 [16384][1152]
#define OB_BMAT (OB_ABUF + MT*KA*2)              // bf16 [1024][1152]
#define OB_BMP  (OB_BMAT + HD*KA*2)              // bf16 [128][1024]
#define OB_BU   (OB_BMP  + N2*HD*2)              // f32  [16384][128]
#define OB_FR   (OB_BU   + MT*N2*4)              // f32  [NCH][NG]
#define OB_FI   (OB_FR   + NG*NCH*4)
#define OB_CR   (OB_FI   + NG*NCH*4)
#define OB_CI   (OB_CR   + NG*NCH*4)
#define OB_WB   (OB_CI   + NG*NCH*4)             // bf16 [1024][1024] raw W
#define OB_CCT  (OB_WB   + HD*HD*2)              // bf16 [128][1024]  CC^T
// end ~ 52.4 MB

__device__ __forceinline__ unsigned short f2bf(float f) {
    unsigned u = __float_as_uint(f);
    u = (u + 0x7FFFu + ((u >> 16) & 1u)) >> 16;
    return (unsigned short)u;
}

__device__ __forceinline__ void lbar_of(int n, const float* __restrict__ logLr,
                                        const float* __restrict__ Li, float dt,
                                        float& ar, float& ai) {
    float lr  = -expf(logLr[n]);
    float mag = expf(lr * dt);
    float ang = Li[n] * dt;
    ar = mag * cosf(ang);
    ai = mag * sinf(ang);
}

// ---------------- fused prep: cast x / D*W / dt*B / raw W / CC^T ------------
__global__ __launch_bounds__(256) void k_prep(const float* __restrict__ x,
                                              const float* __restrict__ W,
                                              const float* __restrict__ Dv,
                                              const float* __restrict__ Br,
                                              const float* __restrict__ Bi,
                                              const float* __restrict__ Cr,
                                              const float* __restrict__ Ci,
                                              const float* __restrict__ log_dt,
                                              unsigned short* __restrict__ Ab,
                                              unsigned short* __restrict__ Bm,
                                              unsigned short* __restrict__ Bp,
                                              unsigned short* __restrict__ Wb,
                                              unsigned short* __restrict__ CCT) {
    __shared__ float T[64][65];
    const int blk = blockIdx.x;
    if (blk < 8192) {
        size_t idx = ((size_t)blk * 256 + threadIdx.x) * 8;
        int m = (int)(idx >> 10), k = (int)(idx & 1023);
        float4 v0 = *(const float4*)&x[idx];
        float4 v1 = *(const float4*)&x[idx + 4];
        short8 s;
        s[0]=f2bf(v0.x); s[1]=f2bf(v0.y); s[2]=f2bf(v0.z); s[3]=f2bf(v0.w);
        s[4]=f2bf(v1.x); s[5]=f2bf(v1.y); s[6]=f2bf(v1.z); s[7]=f2bf(v1.w);
        *(short8*)&Ab[(size_t)m * KA + k] = s;
    } else if (blk < 8704) {
        size_t idx = ((size_t)(blk - 8192) * 256 + threadIdx.x) * 8;
        int h = (int)(idx >> 10), k = (int)(idx & 1023);
        float4 v0 = *(const float4*)&W[idx];
        float4 v1 = *(const float4*)&W[idx + 4];
        float4 d0 = *(const float4*)&Dv[k];
        float4 d1 = *(const float4*)&Dv[k + 4];
        short8 s;
        s[0]=f2bf(v0.x*d0.x); s[1]=f2bf(v0.y*d0.y); s[2]=f2bf(v0.z*d0.z); s[3]=f2bf(v0.w*d0.w);
        s[4]=f2bf(v1.x*d1.x); s[5]=f2bf(v1.y*d1.y); s[6]=f2bf(v1.z*d1.z); s[7]=f2bf(v1.w*d1.w);
        *(short8*)&Bm[(size_t)h * KA + k] = s;
    } else if (blk < 8768) {
        size_t idx = ((size_t)(blk - 8704) * 256 + threadIdx.x) * 8;
        int n2 = (int)(idx >> 10), k = (int)(idx & 1023);
        float dt = expf(log_dt[0]);
        const float* src = (n2 < NS) ? &Br[(size_t)n2 * HD + k] : &Bi[(size_t)(n2 - NS) * HD + k];
        float4 v0 = *(const float4*)&src[0];
        float4 v1 = *(const float4*)&src[4];
        short8 s;
        s[0]=f2bf(v0.x*dt); s[1]=f2bf(v0.y*dt); s[2]=f2bf(v0.z*dt); s[3]=f2bf(v0.w*dt);
        s[4]=f2bf(v1.x*dt); s[5]=f2bf(v1.y*dt); s[6]=f2bf(v1.z*dt); s[7]=f2bf(v1.w*dt);
        *(short8*)&Bp[(size_t)n2 * HD + k] = s;
    } else if (blk < 9280) {
        size_t idx = ((size_t)(blk - 8768) * 256 + threadIdx.x) * 8;
        float4 v0 = *(const float4*)&W[idx];
        float4 v1 = *(const float4*)&W[idx + 4];
        short8 s;
        s[0]=f2bf(v0.x); s[1]=f2bf(v0.y); s[2]=f2bf(v0.z); s[3]=f2bf(v0.w);
        s[4]=f2bf(v1.x); s[5]=f2bf(v1.y); s[6]=f2bf(v1.z); s[7]=f2bf(v1.w);
        *(short8*)&Wb[idx] = s;
    } else {
        const int local = blk - 9280;
        const int h0 = (local & 15) * 64;
        const int half = local >> 4;          // 0: Cr, 1: -Ci
        const float* src = half ? Ci : Cr;
        const float sgn = half ? -1.f : 1.f;
        const int tid = threadIdx.x;
        const int j = tid & 63, i4 = tid >> 6;
        #pragma unroll
        for (int p = 0; p < 16; ++p) {
            int i = p * 4 + i4;
            T[i][j] = src[(size_t)(h0 + i) * NS + j];
        }
        __syncthreads();
        #pragma unroll
        for (int p = 0; p < 16; ++p) {
            int jj = p * 4 + i4;              // n within half
            CCT[(size_t)(half * NS + jj) * HD + h0 + j] = f2bf(sgn * T[j][jj]);
        }
    }
}

// ---------------- ring-pipelined GEMM body (small GEMMs only) ---------------
template<int KTOT>
__device__ __forceinline__ void gemm_ring(const unsigned short* __restrict__ A, int lda,
                                          const unsigned short* __restrict__ B, int ldb,
                                          void* __restrict__ outp, int ldo, int bf16out,
                                          int m0, int n0,
                                          unsigned short* At_base, unsigned short* Bt_base) {
    constexpr int T = KTOT / 32;
    const int tid = threadIdx.x, wv = tid >> 6, ln = tid & 63;
    const int wr = wv >> 1, wc = wv & 1;
    const int r16 = ln & 15, kg = ln >> 4;
    f32x4 zero = {0.f, 0.f, 0.f, 0.f};
    f32x4 acc[4][4];
    #pragma unroll
    for (int i = 0; i < 4; ++i)
        #pragma unroll
        for (int j = 0; j < 4; ++j) acc[i][j] = zero;

    auto STAGE = [&](int t, int s) {
        const int kt = t * 32;
        #pragma unroll
        for (int i = 0; i < 2; ++i) {
            int e = i * 4096 + wv * 1024 + ln * 16;
            int row = e >> 6, kb = e & 63;
            const char* ga = (const char*)A + ((size_t)(m0 + row) * lda + kt) * 2 + kb;
            __builtin_amdgcn_global_load_lds(
                (const __attribute__((address_space(1))) void*)ga,
                (__attribute__((address_space(3))) void*)((char*)At_base + s * 8192 + i * 4096 + wv * 1024),
                16, 0, 0);
            const char* gb = (const char*)B + ((size_t)(n0 + row) * ldb + kt) * 2 + kb;
            __builtin_amdgcn_global_load_lds(
                (const __attribute__((address_space(1))) void*)gb,
                (__attribute__((address_space(3))) void*)((char*)Bt_base + s * 8192 + i * 4096 + wv * 1024),
                16, 0, 0);
        }
    };

    STAGE(0, 0); STAGE(1, 1); STAGE(2, 2);
    int s = 0;
    for (int t = 0; t < T; ++t) {
        if (t + 2 < T)      asm volatile("s_waitcnt vmcnt(8)" ::: "memory");
        else if (t + 1 < T) asm volatile("s_waitcnt vmcnt(4)" ::: "memory");
        else                asm volatile("s_waitcnt vmcnt(0)" ::: "memory");
        __builtin_amdgcn_s_barrier();
        asm volatile("" ::: "memory");
        short8 af[4], bfr[4];
        #pragma unroll
        for (int i = 0; i < 4; ++i) {
            af[i]  = *(const short8*)&At_base[s * 4096 + (wr * 64 + i * 16 + r16) * 32 + kg * 8];
            bfr[i] = *(const short8*)&Bt_base[s * 4096 + (wc * 64 + i * 16 + r16) * 32 + kg * 8];
        }
        __builtin_amdgcn_s_setprio(1);
        #pragma unroll
        for (int i = 0; i < 4; ++i)
            #pragma unroll
            for (int j = 0; j < 4; ++j)
                acc[i][j] = __builtin_amdgcn_mfma_f32_16x16x32_bf16(af[i], bfr[j], acc[i][j], 0, 0, 0);
        __builtin_amdgcn_s_setprio(0);
        asm volatile("" ::: "memory");
        __builtin_amdgcn_s_barrier();
        if (t + 3 < T) STAGE(t + 3, s);
        if (++s == 3) s = 0;
    }
    #pragma unroll
    for (int j = 0; j < 4; ++j) {
        int col = n0 + wc * 64 + j * 16 + r16;
        #pragma unroll
        for (int i = 0; i < 4; ++i) {
            #pragma unroll
            for (int r = 0; r < 4; ++r) {
                int row = m0 + wr * 64 + i * 16 + kg * 4 + r;
                if (bf16out) ((unsigned short*)outp)[(size_t)row * ldo + col] = f2bf(acc[i][j][r]);
                else         ((float*)outp)[(size_t)row * ldo + col] = acc[i][j][r];
            }
        }
    }
}

// fused small GEMMs (N=128, K=1024) + carry pass fused into Bu epilogue:
// blocks [0,128):  Bu = Abuf @ Bmp^T (f32), then per-chunk carries from L2-hot Bu
// blocks [128,136): E2T = Wb @ CCT^T -> Bmat+HD (bf16)
__global__ __launch_bounds__(256) void k_gemm_small(const unsigned short* __restrict__ Abuf,
                                                    const unsigned short* __restrict__ Bmp,
                                                    const unsigned short* __restrict__ Wb,
                                                    const unsigned short* __restrict__ CCT,
                                                    float* __restrict__ Bu,
                                                    unsigned short* __restrict__ BmE2,
                                                    const float* __restrict__ logLr,
                                                    const float* __restrict__ Li,
                                                    const float* __restrict__ log_dt,
                                                    float* __restrict__ Fr,
                                                    float* __restrict__ Fi) {
    __shared__ unsigned short At[3 * 128 * 32];
    __shared__ unsigned short Bt[3 * 128 * 32];
    const int bx = blockIdx.x;
    if (bx < 128) {
        const int m0 = bx * 128;
        gemm_ring<1024>(Abuf, KA, Bmp, 1024, Bu, 128, 0, m0, 0, At, Bt);
        __syncthreads();     // drains vmcnt: all Bu stores of this block at L2
        // fused carry: 8 chunks x 64 n = 512 items, 2 per thread
        const int b = m0 >> 11, lch0 = (m0 & 2047) >> 4;
        const float dt = expf(log_dt[0]);
        #pragma unroll
        for (int w = 0; w < 2; ++w) {
            int item = w * 256 + threadIdx.x;
            int ch_l = item >> 6, n = item & 63;
            float ar, ai; lbar_of(n, logLr, Li, dt, ar, ai);
            float sr = 0.f, si = 0.f;
            size_t base = ((size_t)m0 + ch_l * CHL) * N2;
            #pragma unroll 4
            for (int j = 0; j < CHL; ++j) {
                float ur = Bu[base + j * N2 + n];
                float ui = Bu[base + j * N2 + NS + n];
                float nr = ar * sr - ai * si + ur;
                float ni = ar * si + ai * sr + ui;
                sr = nr; si = ni;
            }
            int fi = (lch0 + ch_l) * NG + b * 64 + n;
            Fr[fi] = sr; Fi[fi] = si;
        }
    } else {
        gemm_ring<1024>(Wb, 1024, CCT, 1024, BmE2, KA, 1, (bx - 128) * 128, 0, At, Bt);
    }
}

// ---------------- wave-parallel carry scan (affine composition) -------------
// chain g: s_{ch+1} = A16*s_ch + F[ch]; f_ch == (alpha=A16, beta=F[ch]).
// 1 wave per chain, lane = 2 chunks; inclusive Hillis-Steele scan on (a,b):
// cur∘prev = (a_c*a_p, a_c*b_p + b_c).
__global__ __launch_bounds__(512) void k_scan2w(const float* __restrict__ Fr,
                                                const float* __restrict__ Fi,
                                                const float* __restrict__ logLr,
                                                const float* __restrict__ Li,
                                                const float* __restrict__ log_dt,
                                                float* __restrict__ CexR,
                                                float* __restrict__ CexI,
                                                float* __restrict__ out_tail) {
    const int wv = threadIdx.x >> 6, l = threadIdx.x & 63;
    const int g = blockIdx.x * 8 + wv;          // 64 blocks * 8 waves = 512 chains
    const int n = g & 63;
    const float dt = expf(log_dt[0]);
    float ar, ai; lbar_of(n, logLr, Li, dt, ar, ai);
    float Ar = ar, Ai = ai;                      // A16 = a^CHL via 4 squarings
    #pragma unroll
    for (int s = 0; s < 4; ++s) { float nr = Ar*Ar - Ai*Ai; Ai = 2.f*Ar*Ai; Ar = nr; }
    const int ch0 = 2 * l;
    float f0r = Fr[ch0 * NG + g],       f0i = Fi[ch0 * NG + g];
    float f1r = Fr[(ch0 + 1) * NG + g], f1i = Fi[(ch0 + 1) * NG + g];
    // per-lane pair Q = f_{2l+1} ∘ f_{2l}
    float qar = Ar*Ar - Ai*Ai,           qai = 2.f*Ar*Ai;
    float qbr = Ar*f0r - Ai*f0i + f1r,   qbi = Ar*f0i + Ai*f0r + f1i;
    #pragma unroll
    for (int d = 1; d < 64; d <<= 1) {
        float par = __shfl_up(qar, d, 64);
        float pai = __shfl_up(qai, d, 64);
        float pbr = __shfl_up(qbr, d, 64);
        float pbi = __shfl_up(qbi, d, 64);
        if (l >= d) {
            float nar = qar*par - qai*pai;
            float nai = qar*pai + qai*par;
            float nbr = qar*pbr - qai*pbi + qbr;
            float nbi = qar*pbi + qai*pbr + qbi;
            qar = nar; qai = nai; qbr = nbr; qbi = nbi;
        }
    }
    // exclusive prefix (state entering chunk 2l)
    float ebr = __shfl_up(qbr, 1, 64);
    float ebi = __shfl_up(qbi, 1, 64);
    if (l == 0) { ebr = 0.f; ebi = 0.f; }
    CexR[ch0 * NG + g] = ebr;  CexI[ch0 * NG + g] = ebi;
    CexR[(ch0 + 1) * NG + g] = Ar*ebr - Ai*ebi + f0r;
    CexI[(ch0 + 1) * NG + g] = Ar*ebi + Ai*ebr + f0i;
    if (l == 63) { out_tail[g] = qbr; out_tail[NG + g] = qbi; }
}

// ---------------- scan pass C: replay with carry, write bf16 S into Abuf ----
__global__ __launch_bounds__(256) void k_scan3(const float* __restrict__ Bu,
                                               const float* __restrict__ CexR,
                                               const float* __restrict__ CexI,
                                               const float* __restrict__ logLr,
                                               const float* __restrict__ Li,
                                               const float* __restrict__ log_dt,
                                               unsigned short* __restrict__ Ab) {
    int g = blockIdx.x * 256 + threadIdx.x;
    int n = g & 63, ch = (g >> 6) & (NCH - 1), b = g >> 13;
    float dt = expf(log_dt[0]);
    float ar, ai; lbar_of(n, logLr, Li, dt, ar, ai);
    int ci_idx = ch * NG + b * 64 + n;
    float sr = CexR[ci_idx], si = CexI[ci_idx];
    size_t base = ((size_t)b * LS + ch * CHL);
    #pragma unroll 4
    for (int j = 0; j < CHL; ++j) {
        size_t m = base + j;
        float ur = Bu[m * N2 + n];
        float ui = Bu[m * N2 + NS + n];
        float nr = ar * sr - ai * si + ur;
        float ni = ar * si + ai * sr + ui;
        sr = nr; si = ni;
        Ab[m * KA + HD + n]      = f2bf(sr);
        Ab[m * KA + HD + NS + n] = f2bf(si);
    }
}

// ---------------- big GEMM: proven round-2 single-buffer structure ----------
// out = Abuf @ Bmat^T + bias  (M=16384, N=1024, K=1152)
__global__ __launch_bounds__(256) void k_gemm_big(const unsigned short* __restrict__ A,
                                                  const unsigned short* __restrict__ B,
                                                  const float* __restrict__ bias,
                                                  float* __restrict__ out) {
    __shared__ unsigned short At[128 * 32];
    __shared__ unsigned short Bt[128 * 32];
    const int m0 = blockIdx.x * 128, n0 = blockIdx.y * 128;
    const int tid = threadIdx.x, wv = tid >> 6, ln = tid & 63;
    const int wr = wv >> 1, wc = wv & 1;
    const int r16 = ln & 15, kg = ln >> 4;
    f32x4 zero = {0.f, 0.f, 0.f, 0.f};
    f32x4 acc[4][4];
    #pragma unroll
    for (int i = 0; i < 4; ++i)
        #pragma unroll
        for (int j = 0; j < 4; ++j) acc[i][j] = zero;

    for (int kt = 0; kt < KA; kt += 32) {
        #pragma unroll
        for (int i = 0; i < 2; ++i) {
            int e = i * 4096 + wv * 1024 + ln * 16;
            int row = e >> 6, kb = e & 63;
            const char* ga = (const char*)A + ((size_t)(m0 + row) * KA + kt) * 2 + kb;
            __builtin_amdgcn_global_load_lds(
                (const __attribute__((address_space(1))) void*)ga,
                (__attribute__((address_space(3))) void*)((char*)At + i * 4096 + wv * 1024),
                16, 0, 0);
            const char* gb = (const char*)B + ((size_t)(n0 + row) * KA + kt) * 2 + kb;
            __builtin_amdgcn_global_load_lds(
                (const __attribute__((address_space(1))) void*)gb,
                (__attribute__((address_space(3))) void*)((char*)Bt + i * 4096 + wv * 1024),
                16, 0, 0);
        }
        __syncthreads();
        short8 af[4], bfr[4];
        #pragma unroll
        for (int i = 0; i < 4; ++i) {
            af[i]  = *(const short8*)&At[(wr * 64 + i * 16 + r16) * 32 + kg * 8];
            bfr[i] = *(const short8*)&Bt[(wc * 64 + i * 16 + r16) * 32 + kg * 8];
        }
        #pragma unroll
        for (int i = 0; i < 4; ++i)
            #pragma unroll
            for (int j = 0; j < 4; ++j)
                acc[i][j] = __builtin_amdgcn_mfma_f32_16x16x32_bf16(af[i], bfr[j], acc[i][j], 0, 0, 0);
        __syncthreads();
    }
    // epilogue: C/D layout col=lane&15, row=(lane>>4)*4+reg  [m89/m91]
    #pragma unroll
    for (int j = 0; j < 4; ++j) {
        int col = n0 + wc * 64 + j * 16 + r16;
        float bv = bias[col];
        #pragma unroll
        for (int i = 0; i < 4; ++i) {
            #pragma unroll
            for (int r = 0; r < 4; ++r) {
                int row = m0 + wr * 64 + i * 16 + kg * 4 + r;
                out[(size_t)row * HD + col] = acc[i][j][r] + bv;
            }
        }
    }
}

extern "C" void kernel_launch(void* const* d_in, const int* in_sizes, int n_in,
                              void* d_out, int out_size, void* d_ws, size_t ws_size,
                              hipStream_t stream) {
    const float* x      = (const float*)d_in[0];
    const float* logLr  = (const float*)d_in[1];
    const float* Li     = (const float*)d_in[2];
    const float* Br     = (const float*)d_in[3];
    const float* Bi     = (const float*)d_in[4];
    const float* Cr     = (const float*)d_in[5];
    const float* Ci     = (const float*)d_in[6];
    const float* Dv     = (const float*)d_in[7];
    const float* log_dt = (const float*)d_in[8];
    const float* W      = (const float*)d_in[9];
    const float* bo     = (const float*)d_in[10];
    float* out = (float*)d_out;
    char*  ws  = (char*)d_ws;

    unsigned short* Abuf = (unsigned short*)(ws + OB_ABUF);
    unsigned short* Bmat = (unsigned short*)(ws + OB_BMAT);
    unsigned short* Bmp  = (unsigned short*)(ws + OB_BMP);
    float* Bu   = (float*)(ws + OB_BU);
    float* Fr   = (float*)(ws + OB_FR);
    float* Fi   = (float*)(ws + OB_FI);
    float* CexR = (float*)(ws + OB_CR);
    float* CexI = (float*)(ws + OB_CI);
    unsigned short* Wb   = (unsigned short*)(ws + OB_WB);
    unsigned short* CCT  = (unsigned short*)(ws + OB_CCT);

    k_prep <<<9312, 256, 0, stream>>>(x, W, Dv, Br, Bi, Cr, Ci, log_dt, Abuf, Bmat, Bmp, Wb, CCT);
    k_gemm_small<<<136, 256, 0, stream>>>(Abuf, Bmp, Wb, CCT, Bu, Bmat + HD,
                                          logLr, Li, log_dt, Fr, Fi);
    k_scan2w<<<64, 512, 0, stream>>>(Fr, Fi, logLr, Li, log_dt, CexR, CexI, out + (size_t)MT * HD);
    k_scan3<<<(NB * NS * NCH) / 256, 256, 0, stream>>>(Bu, CexR, CexI, logLr, Li, log_dt, Abuf);
    k_gemm_big<<<dim3(MT / 128, HD / 128), 256, 0, stream>>>(Abuf, Bmat, bo, out);
}